// Round 12
// baseline (571.997 us; speedup 1.0000x reference)
//
#include <hip/hip_runtime.h>
#include <hip/hip_bf16.h>
#include <cstdint>
#include <cstddef>

#define D 64
#define V_N 4000
#define E_N 40000
#define G_N 40
#define NPG 100          // nodes per graph (contiguous)
#define NODE_IN 74
#define EDGE_IN 128
#define NSTEPS 6
#define S2S_ITERS 6

typedef unsigned short u16b;
typedef __attribute__((ext_vector_type(8))) short bf16x8;
typedef __attribute__((ext_vector_type(4))) float f32x4;

__device__ __forceinline__ float b2f(u16b u) {
  union { unsigned int i; float f; } v; v.i = ((unsigned int)u) << 16; return v.f;
}
__device__ __forceinline__ u16b f2b(float f) {
  union { unsigned int i; float f; } v; v.f = f;
  unsigned int r = (v.i + 0x7fffu + ((v.i >> 16) & 1u)) >> 16;
  return (u16b)r;
}
// fast transcendentals (v_exp + fast rcp): ~1 ulp fp32, << bf16 noise
__device__ __forceinline__ float sigf(float x) {
  return __fdividef(1.f, 1.f + __expf(-x));
}
__device__ __forceinline__ float tanhf_f(float x) {
  return 1.f - 2.f * __fdividef(1.f, __expf(2.f * x) + 1.f);
}

// ---------------- h = relu(node_feats @ W_proj + b_proj) ----------------
__global__ void k_proj(const float* __restrict__ nf, const float* __restrict__ W,
                       const float* __restrict__ b, float* __restrict__ h) {
  int v = blockIdx.x, o = threadIdx.x;            // 64 threads
  const float* row = nf + v * NODE_IN;
  float acc = b[o];
  for (int i = 0; i < NODE_IN; ++i)
    acc += row[i] * W[i * D + o];
  h[v * D + o] = fmaxf(acc, 0.f);
}

// ------- prep: all weight repacks (fragments + packed LSTM + bias sums) -----
__global__ void k_prep(const float* __restrict__ W_ih, const float* __restrict__ W_hh,
                       const float* __restrict__ W_e2, const float* __restrict__ W_e1,
                       const float* __restrict__ Wih0, const float* __restrict__ Whh0,
                       const float* __restrict__ bih0, const float* __restrict__ bhh0,
                       const float* __restrict__ Wih1, const float* __restrict__ Whh1,
                       const float* __restrict__ bih1, const float* __restrict__ bhh1,
                       const float* __restrict__ Wih2, const float* __restrict__ Whh2,
                       const float* __restrict__ bih2, const float* __restrict__ bhh2,
                       u16b* __restrict__ W2s,
                       unsigned* __restrict__ WP0, unsigned* __restrict__ WP1,
                       unsigned* __restrict__ WP2, float* __restrict__ bsum,
                       u16b* __restrict__ WIHf, u16b* __restrict__ WHHf,
                       u16b* __restrict__ W1f) {
  int idx = blockIdx.x * 256 + threadIdx.x;       // grid covers 524288
  if (idx < 524288) {                             // W_e2 -> Phase-A fragments
    int q = idx >> 17, rem = idx & 131071;
    int t16 = rem >> 10, rem2 = rem & 1023;
    int kbA = rem2 >> 9, rem3 = rem2 & 511;
    int lane = rem3 >> 3, jA = rem3 & 7;
    int m15 = lane & 15, quadA = lane >> 4;
    int m_idx = t16 * 16 + m15;
    int i = kbA * 32 + quadA * 8 + jA;
    int kb = m_idx >> 9, quadB = (m_idx >> 7) & 3;
    int n15B = (m_idx >> 3) & 15, j = m_idx & 7;
    int k = kb * 32 + quadB * 8 + j;
    int o = q * 16 + n15B;
    W2s[idx] = f2b(W_e2[k * 4096 + i * 64 + o]);
  }
  if (idx < 24576) {                              // WP0: layer0 packed bf16
    int kh = idx >> 8, tt = idx & 255;
    int half = kh / 48, kk = kh - half * 48;
    int k0 = half * 96 + 2 * kk;
    float v0 = (k0 < 128) ? Wih0[tt * 128 + k0] : Whh0[tt * 64 + (k0 - 128)];
    float v1 = (k0 + 1 < 128) ? Wih0[tt * 128 + k0 + 1] : Whh0[tt * 64 + (k0 - 127)];
    WP0[idx] = (unsigned)f2b(v0) | ((unsigned)f2b(v1) << 16);
  }
  if (idx < 16384) {                              // WP1/WP2: layers 1,2
    int kh = idx >> 8, tt = idx & 255;
    int half = kh >> 5, kk = kh & 31;
    int k0 = half * 64 + 2 * kk;
    float a0 = (k0 < 64) ? Wih1[tt * 64 + k0] : Whh1[tt * 64 + (k0 - 64)];
    float a1 = (k0 + 1 < 64) ? Wih1[tt * 64 + k0 + 1] : Whh1[tt * 64 + (k0 - 63)];
    WP1[idx] = (unsigned)f2b(a0) | ((unsigned)f2b(a1) << 16);
    float c0 = (k0 < 64) ? Wih2[tt * 64 + k0] : Whh2[tt * 64 + (k0 - 64)];
    float c1 = (k0 + 1 < 64) ? Wih2[tt * 64 + k0 + 1] : Whh2[tt * 64 + (k0 - 63)];
    WP2[idx] = (unsigned)f2b(c0) | ((unsigned)f2b(c1) << 16);
  }
  if (idx < 12288) {                              // GRU weights -> A-fragments
    int j = idx & 7, lane = (idx >> 3) & 63, tk = idx >> 9;
    int gt = tk >> 1, kb = tk & 1;
    int gate = gt * 16 + (lane & 15);
    int i = kb * 32 + ((lane >> 4) << 3) + j;
    WIHf[idx] = f2b(W_ih[gate * 64 + i]);
    WHHf[idx] = f2b(W_hh[gate * 64 + i]);
  }
  if (idx < 16384) {                              // W_e1 -> B-fragments
    int j = idx & 7, lane = (idx >> 3) & 63, tk = idx >> 9;
    int nt = tk >> 2, kb = tk & 3;
    int n = nt * 16 + (lane & 15);
    int i = kb * 32 + ((lane >> 4) << 3) + j;
    W1f[idx] = f2b(W_e1[i * 128 + n]);
  }
  if (idx < 256) bsum[idx] = bih0[idx] + bhh0[idx];
  else if (idx < 512) bsum[idx] = bih1[idx - 256] + bhh1[idx - 256];
  else if (idx < 768) bsum[idx] = bih2[idx - 512] + bhh2[idx - 512];
}

// -------- r1 = relu(edge_feats @ W_e1 + b_e1) -> bf16, via MFMA -------------
__global__ __launch_bounds__(256) void k_edge2(
    const float* __restrict__ ef, const u16b* __restrict__ W1f,
    const float* __restrict__ b_e1, u16b* __restrict__ r1b) {
  __shared__ __align__(16) u16b R[64 * 128];      // 16 KB
  int t = threadIdx.x, w = t >> 6, lane = t & 63;
  int n15 = lane & 15, quad = lane >> 4;
  int e0 = blockIdx.x * 64;
  int ew = e0 + w * 16;                           // wave's 16-edge m-tile
  bf16x8 aF[4];
  const float* ep = ef + (size_t)(ew + n15) * 128 + quad * 8;
#pragma unroll
  for (int kb = 0; kb < 4; ++kb) {
    union { bf16x8 v; u16b s[8]; } au;
#pragma unroll
    for (int j = 0; j < 8; ++j) au.s[j] = f2b(ep[kb * 32 + j]);
    aF[kb] = au.v;
  }
  const uint4* B4 = (const uint4*)W1f;
#pragma unroll
  for (int nt = 0; nt < 8; ++nt) {
    f32x4 acc = {0.f, 0.f, 0.f, 0.f};
#pragma unroll
    for (int kb = 0; kb < 4; ++kb) {
      union { uint4 u; bf16x8 v; } bu;
      bu.u = B4[(nt * 4 + kb) * 64 + lane];
      acc = __builtin_amdgcn_mfma_f32_16x16x32_bf16(aF[kb], bu.v, acc, 0, 0, 0);
    }
    float bb = b_e1[nt * 16 + n15];
#pragma unroll
    for (int r = 0; r < 4; ++r) {
      int eoff = w * 16 + quad * 4 + r;           // D row = edge offset
      R[eoff * 128 + nt * 16 + n15] = f2b(fmaxf(acc[r] + bb, 0.f));
    }
  }
  __syncthreads();
  const uint4* Rs = (const uint4*)R;
  uint4* out4 = (uint4*)(r1b + (size_t)e0 * 128);
  for (int i = t; i < 1024; i += 256) out4[i] = Rs[i];
}

// ---------------- counting sort of edges by key (src or dst) ----------------
__global__ void k_zero(int* __restrict__ cnt) {   // 4096 bins
  cnt[blockIdx.x * 256 + threadIdx.x] = 0;
}
__global__ void k_hist(const int* __restrict__ key, int* __restrict__ cnt) {
  int e = blockIdx.x * 256 + threadIdx.x;
  if (e < E_N) atomicAdd(&cnt[key[e]], 1);
}
__global__ __launch_bounds__(256) void k_scan(const int* __restrict__ cnt,
                                              int* __restrict__ offs,
                                              int* __restrict__ cursor) {
  __shared__ int part[256];
  int t = threadIdx.x;                            // single block
  int local[16], s = 0;
#pragma unroll
  for (int b = 0; b < 16; ++b) { local[b] = cnt[t * 16 + b]; s += local[b]; }
  part[t] = s;
  __syncthreads();
  for (int off = 1; off < 256; off <<= 1) {
    int v = (t >= off) ? part[t - off] : 0;
    __syncthreads();
    part[t] += v;
    __syncthreads();
  }
  int run = part[t] - s;                          // exclusive base
#pragma unroll
  for (int b = 0; b < 16; ++b) {
    offs[t * 16 + b] = run;
    cursor[t * 16 + b] = run;
    run += local[b];
  }
}
__global__ void k_scatter(const int* __restrict__ key, int* __restrict__ cursor,
                          int* __restrict__ order) {
  int e = blockIdx.x * 256 + threadIdx.x;
  if (e < E_N) {
    int pos = atomicAdd(&cursor[key[e]], 1);
    order[pos] = e;
  }
}

// ---------------- zero agg once (fallback path) ----------------
__global__ void k_zero_agg(float* __restrict__ agg) {
  agg[blockIdx.x * 256 + threadIdx.x] = 0.f;
}

// ------ block = 16 nodes x 1 o-quarter, 512 threads (8 waves).
// Phase A: T[16n][128k][16o] + ybias via MFMA. Phase B: edge-tile MFMA.
// mode 0: atomic scatter to agg; mode 1: bf16 msg store; mode 2: fp32 msg.
__global__ __launch_bounds__(512) void k_msg8(
    const float* __restrict__ h, const u16b* __restrict__ r1b,
    const u16b* __restrict__ W2s, const float* __restrict__ b_e2,
    const int* __restrict__ offs, const int* __restrict__ order,
    const int* __restrict__ dst, float* __restrict__ agg,
    float* __restrict__ msgf, u16b* __restrict__ msgb, int mode) {
  __shared__ __align__(16) u16b TB[16 * 2048];    // 64 KB exactly
  __shared__ float ybs[16][16];
  int t = threadIdx.x;
  int g = blockIdx.x >> 2, q = blockIdx.x & 3;
  int v0 = g * 16;
  int w = t >> 6, lane = t & 63;
  int n15 = lane & 15, quad = lane >> 4;

  bf16x8 hb[2];
  {
    union { bf16x8 v; u16b s[8]; } b0, b1;
    const float* hp = h + (v0 + n15) * 64 + quad * 8;
#pragma unroll
    for (int j = 0; j < 8; ++j) { b0.s[j] = f2b(hp[j]); b1.s[j] = f2b(hp[32 + j]); }
    hb[0] = b0.v; hb[1] = b1.v;
  }
  if (w == 0) {
    union { bf16x8 v; u16b s[8]; } a0, a1;
#pragma unroll
    for (int j = 0; j < 8; ++j) {
      a0.s[j] = f2b(b_e2[(quad * 8 + j) * 64 + q * 16 + n15]);
      a1.s[j] = f2b(b_e2[(32 + quad * 8 + j) * 64 + q * 16 + n15]);
    }
    f32x4 acc = {0.f, 0.f, 0.f, 0.f};
    acc = __builtin_amdgcn_mfma_f32_16x16x32_bf16(a0.v, hb[0], acc, 0, 0, 0);
    acc = __builtin_amdgcn_mfma_f32_16x16x32_bf16(a1.v, hb[1], acc, 0, 0, 0);
#pragma unroll
    for (int r = 0; r < 4; ++r) ybs[n15][quad * 4 + r] = acc[r];
  }
  const uint4* W4 = (const uint4*)(W2s) + (size_t)q * 16384;
#pragma unroll 4
  for (int tt = 0; tt < 16; ++tt) {
    int t16 = w * 16 + tt;
    uint4 a0 = W4[t16 * 128 + lane];
    uint4 a1 = W4[t16 * 128 + 64 + lane];
    union { uint4 u; bf16x8 v; } c0, c1;
    c0.u = a0; c1.u = a1;
    f32x4 acc = {0.f, 0.f, 0.f, 0.f};
    acc = __builtin_amdgcn_mfma_f32_16x16x32_bf16(c0.v, hb[0], acc, 0, 0, 0);
    acc = __builtin_amdgcn_mfma_f32_16x16x32_bf16(c1.v, hb[1], acc, 0, 0, 0);
    int flat = (t16 * 16 + quad * 4 + n15 * 8) & 2047;
    uint2 pk;
    pk.x = (unsigned)f2b(acc[0]) | ((unsigned)f2b(acc[1]) << 16);
    pk.y = (unsigned)f2b(acc[2]) | ((unsigned)f2b(acc[3]) << 16);
    *(uint2*)&TB[n15 * 2048 + flat] = pk;
  }
  __syncthreads();

  for (int ni = 0; ni < 2; ++ni) {
    int n = w * 2 + ni;
    int v = v0 + n;
    int e0 = offs[v], e1 = offs[v + 1];
    if (e0 >= e1) continue;
    bf16x8 bfr[4];
#pragma unroll
    for (int kb = 0; kb < 4; ++kb) {
      int flat = (((kb * 64 + quad * 16 + n15) << 3) + n * 8) & 2047;
      bfr[kb] = *(const bf16x8*)&TB[n * 2048 + flat];
    }
    float yb = ybs[n][n15];
    for (int jt = e0; jt < e1; jt += 16) {
      int je = jt + n15; if (je > e1 - 1) je = e1 - 1;
      int e = order[je];
      f32x4 acc = {0.f, 0.f, 0.f, 0.f};
#pragma unroll
      for (int kb = 0; kb < 4; ++kb) {
        union { uint4 u; bf16x8 v; } af;
        af.u = *(const uint4*)(r1b + e * 128 + kb * 32 + quad * 8);
        acc = __builtin_amdgcn_mfma_f32_16x16x32_bf16(af.v, bfr[kb], acc, 0, 0, 0);
      }
      if (mode == 2) {
#pragma unroll
        for (int r = 0; r < 4; ++r) {
          int row = quad * 4 + r;
          if (jt + row < e1) {
            int er = order[jt + row];
            msgf[(size_t)er * 64 + q * 16 + n15] = acc[r] + yb;
          }
        }
      } else if (mode == 1) {
#pragma unroll
        for (int r = 0; r < 4; ++r) {
          int row = quad * 4 + r;
          if (jt + row < e1) {
            int er = order[jt + row];
            msgb[(size_t)er * 64 + q * 16 + n15] = f2b(acc[r] + yb);
          }
        }
      } else {
#pragma unroll
        for (int r = 0; r < 4; ++r) {
          int row = quad * 4 + r;
          if (jt + row < e1) {
            int er = order[jt + row];
            atomicAdd(&agg[dst[er] * 64 + q * 16 + n15], acc[r] + yb);
          }
        }
      }
    }
  }
}

// -------- fused dst-gather + GRU via MFMA: 4 waves/block, wave = 4 nodes ----
__global__ __launch_bounds__(256) void k_gru4(
    float* __restrict__ agg, float* __restrict__ h,
    const float* __restrict__ msgf, const u16b* __restrict__ msgb, int mode,
    const int* __restrict__ doffs, const int* __restrict__ dorder,
    const u16b* __restrict__ WIHf, const u16b* __restrict__ WHHf,
    const float* __restrict__ b_ih, const float* __restrict__ b_hh,
    const float* __restrict__ b_conv) {
  __shared__ float X[16][64];
  __shared__ float G[4][4][4][68];                // [wave][kind][node][dim]
  int t = threadIdx.x, w = t >> 6, lane = t & 63;
  int n15 = lane & 15, quad = lane >> 4;
  int vb = blockIdx.x * 16 + w * 4;               // wave's 4 nodes
  // gather x = relu(sum msg + b_conv) for the wave's 4 nodes (lane = o)
  float bc_l = b_conv[lane];
  for (int n = 0; n < 4; ++n) {
    int v = vb + n;
    float s = 0.f;
    if (mode == 2) {
      int j0 = doffs[v], j1 = doffs[v + 1];
      for (int j = j0; j < j1; ++j) s += msgf[(size_t)dorder[j] * 64 + lane];
    } else if (mode == 1) {
      int j0 = doffs[v], j1 = doffs[v + 1];
      for (int j = j0; j < j1; ++j) s += b2f(msgb[(size_t)dorder[j] * 64 + lane]);
    } else {
      s = agg[v * 64 + lane];
      agg[v * 64 + lane] = 0.f;                   // reset for next step
    }
    X[w * 4 + n][lane] = fmaxf(s + bc_l, 0.f);
  }
  float hold[4];
#pragma unroll
  for (int n = 0; n < 4; ++n) hold[n] = h[(vb + n) * 64 + lane];
  __syncthreads();
  bf16x8 xB[2], hB[2];
  {
    union { bf16x8 v; u16b s[8]; } bx0, bx1, bh0, bh1;
#pragma unroll
    for (int j = 0; j < 8; ++j) { bx0.s[j] = 0; bx1.s[j] = 0; bh0.s[j] = 0; bh1.s[j] = 0; }
    if (n15 < 4) {
      const float* xp = &X[w * 4 + n15][quad * 8];
      const float* hp = h + (vb + n15) * 64 + quad * 8;
#pragma unroll
      for (int j = 0; j < 8; ++j) {
        bx0.s[j] = f2b(xp[j]);
        bx1.s[j] = f2b(xp[32 + j]);
        bh0.s[j] = f2b(hp[j]);
        bh1.s[j] = f2b(hp[32 + j]);
      }
    }
    xB[0] = bx0.v; xB[1] = bx1.v; hB[0] = bh0.v; hB[1] = bh1.v;
  }
  const uint4* AIH = (const uint4*)WIHf;
  const uint4* AHH = (const uint4*)WHHf;
#pragma unroll
  for (int gt = 0; gt < 8; ++gt) {                // r (0-3) and z (4-7) blocks
    union { uint4 u; bf16x8 v; } a;
    f32x4 acc = {0.f, 0.f, 0.f, 0.f};
    a.u = AIH[(gt * 2 + 0) * 64 + lane];
    acc = __builtin_amdgcn_mfma_f32_16x16x32_bf16(a.v, xB[0], acc, 0, 0, 0);
    a.u = AIH[(gt * 2 + 1) * 64 + lane];
    acc = __builtin_amdgcn_mfma_f32_16x16x32_bf16(a.v, xB[1], acc, 0, 0, 0);
    a.u = AHH[(gt * 2 + 0) * 64 + lane];
    acc = __builtin_amdgcn_mfma_f32_16x16x32_bf16(a.v, hB[0], acc, 0, 0, 0);
    a.u = AHH[(gt * 2 + 1) * 64 + lane];
    acc = __builtin_amdgcn_mfma_f32_16x16x32_bf16(a.v, hB[1], acc, 0, 0, 0);
    int kind = (gt < 4) ? 0 : 1;
    int base = (gt & 3) * 16 + quad * 4;
    if (n15 < 4) {
#pragma unroll
      for (int r = 0; r < 4; ++r) G[w][kind][n15][base + r] = acc[r];
    }
  }
#pragma unroll
  for (int gt = 8; gt < 12; ++gt) {               // n block: keep i/h separate
    union { uint4 u; bf16x8 v; } a;
    f32x4 ai = {0.f, 0.f, 0.f, 0.f}, ah = {0.f, 0.f, 0.f, 0.f};
    a.u = AIH[(gt * 2 + 0) * 64 + lane];
    ai = __builtin_amdgcn_mfma_f32_16x16x32_bf16(a.v, xB[0], ai, 0, 0, 0);
    a.u = AIH[(gt * 2 + 1) * 64 + lane];
    ai = __builtin_amdgcn_mfma_f32_16x16x32_bf16(a.v, xB[1], ai, 0, 0, 0);
    a.u = AHH[(gt * 2 + 0) * 64 + lane];
    ah = __builtin_amdgcn_mfma_f32_16x16x32_bf16(a.v, hB[0], ah, 0, 0, 0);
    a.u = AHH[(gt * 2 + 1) * 64 + lane];
    ah = __builtin_amdgcn_mfma_f32_16x16x32_bf16(a.v, hB[1], ah, 0, 0, 0);
    int base = (gt & 3) * 16 + quad * 4;
    if (n15 < 4) {
#pragma unroll
      for (int r = 0; r < 4; ++r) { G[w][2][n15][base + r] = ai[r]; G[w][3][n15][base + r] = ah[r]; }
    }
  }
  __syncthreads();
  float bi_r = b_ih[lane] + b_hh[lane];
  float bi_z = b_ih[64 + lane] + b_hh[64 + lane];
  float bi_n1 = b_ih[128 + lane], bi_n2 = b_hh[128 + lane];
#pragma unroll
  for (int n = 0; n < 4; ++n) {
    float r = sigf(G[w][0][n][lane] + bi_r);
    float z = sigf(G[w][1][n][lane] + bi_z);
    float nn = tanhf_f(G[w][2][n][lane] + bi_n1 + r * (G[w][3][n][lane] + bi_n2));
    h[(vb + n) * 64 + lane] = (1.f - z) * nn + z * hold[n];
  }
}

// ------- Set2Set: round-10 structure + fast transcendentals -----------------
__global__ __launch_bounds__(512) void k_s2s(
    const float* __restrict__ h,
    const unsigned* __restrict__ WP0, const unsigned* __restrict__ WP1,
    const unsigned* __restrict__ WP2, const float* __restrict__ bsum,
    const float* __restrict__ W_p1, const float* __restrict__ b_p1,
    const float* __restrict__ W_p2, const float* __restrict__ b_p2,
    float* __restrict__ out) {
  int g = blockIdx.x, t = threadIdx.x;            // 512 threads
  int tt = t & 255, half = t >> 8;
  __shared__ float hL[NPG * 65];
  __shared__ float S[320];                        // [q_star(128)|hs0|hs1|hs2]
  __shared__ float csL[3][64];
  __shared__ float gpart[512], att[NPG];
  unsigned w0[48], w1[32], w2[32];
#pragma unroll
  for (int kk = 0; kk < 48; ++kk) w0[kk] = WP0[(half * 48 + kk) * 256 + tt];
#pragma unroll
  for (int kk = 0; kk < 32; ++kk) w1[kk] = WP1[(half * 32 + kk) * 256 + tt];
#pragma unroll
  for (int kk = 0; kk < 32; ++kk) w2[kk] = WP2[(half * 32 + kk) * 256 + tt];
  for (int idx = t; idx < NPG * 64; idx += 512)
    hL[(idx >> 6) * 65 + (idx & 63)] = h[(size_t)g * NPG * 64 + idx];
  if (t < 320) S[t] = 0.f;
  if (t < 192) ((float*)csL)[t] = 0.f;
  __syncthreads();
  for (int it = 0; it < S2S_ITERS; ++it) {
    // ---- layer 0: window S+0 (len 192) ----
    {
      const float* win = S + half * 96;
      float p = 0.f;
#pragma unroll
      for (int kk = 0; kk < 48; ++kk) {
        unsigned wv = w0[kk];
        p += b2f((u16b)(wv & 0xffffu)) * win[2 * kk]
           + b2f((u16b)(wv >> 16)) * win[2 * kk + 1];
      }
      gpart[t] = p;
    }
    __syncthreads();
    if (t < 64) {
      float gi = bsum[t]       + gpart[t]       + gpart[t + 256];
      float gf = bsum[64 + t]  + gpart[64 + t]  + gpart[64 + t + 256];
      float gg = bsum[128 + t] + gpart[128 + t] + gpart[128 + t + 256];
      float go = bsum[192 + t] + gpart[192 + t] + gpart[192 + t + 256];
      float c = sigf(gf) * csL[0][t] + sigf(gi) * tanhf_f(gg);
      csL[0][t] = c;
      S[128 + t] = sigf(go) * tanhf_f(c);
    }
    __syncthreads();
    // ---- layer 1: window S+128 (len 128) ----
    {
      const float* win = S + 128 + half * 64;
      float p = 0.f;
#pragma unroll
      for (int kk = 0; kk < 32; ++kk) {
        unsigned wv = w1[kk];
        p += b2f((u16b)(wv & 0xffffu)) * win[2 * kk]
           + b2f((u16b)(wv >> 16)) * win[2 * kk + 1];
      }
      gpart[t] = p;
    }
    __syncthreads();
    if (t < 64) {
      float gi = bsum[256 + t]       + gpart[t]       + gpart[t + 256];
      float gf = bsum[256 + 64 + t]  + gpart[64 + t]  + gpart[64 + t + 256];
      float gg = bsum[256 + 128 + t] + gpart[128 + t] + gpart[128 + t + 256];
      float go = bsum[256 + 192 + t] + gpart[192 + t] + gpart[192 + t + 256];
      float c = sigf(gf) * csL[1][t] + sigf(gi) * tanhf_f(gg);
      csL[1][t] = c;
      S[192 + t] = sigf(go) * tanhf_f(c);
    }
    __syncthreads();
    // ---- layer 2: window S+192 (len 128) ----
    {
      const float* win = S + 192 + half * 64;
      float p = 0.f;
#pragma unroll
      for (int kk = 0; kk < 32; ++kk) {
        unsigned wv = w2[kk];
        p += b2f((u16b)(wv & 0xffffu)) * win[2 * kk]
           + b2f((u16b)(wv >> 16)) * win[2 * kk + 1];
      }
      gpart[t] = p;
    }
    __syncthreads();
    if (t < 64) {
      float gi = bsum[512 + t]       + gpart[t]       + gpart[t + 256];
      float gf = bsum[512 + 64 + t]  + gpart[64 + t]  + gpart[64 + t + 256];
      float gg = bsum[512 + 128 + t] + gpart[128 + t] + gpart[128 + t + 256];
      float go = bsum[512 + 192 + t] + gpart[192 + t] + gpart[192 + t + 256];
      float c = sigf(gf) * csL[2][t] + sigf(gi) * tanhf_f(gg);
      csL[2][t] = c;
      S[256 + t] = sigf(go) * tanhf_f(c);
    }
    __syncthreads();
    // ---- attention scores (threads 0..99) ----
    if (t < NPG) {
      float e = 0.f;
#pragma unroll 8
      for (int dd = 0; dd < D; ++dd) e += hL[t * 65 + dd] * S[256 + dd];
      att[t] = e;
    }
    __syncthreads();
    // ---- wave 0: softmax + readout + q_star update (wave-synchronous) ----
    if (t < 64) {
      float m = att[t];
      if (t < NPG - 64) m = fmaxf(m, att[t + 64]);
#pragma unroll
      for (int off = 32; off >= 1; off >>= 1) m = fmaxf(m, __shfl_xor(m, off));
      float e1 = __expf(att[t] - m);
      float e2 = (t < NPG - 64) ? __expf(att[t + 64] - m) : 0.f;
      att[t] = e1;
      if (t < NPG - 64) att[t + 64] = e2;
      float s = e1 + e2;
#pragma unroll
      for (int off = 32; off >= 1; off >>= 1) s += __shfl_xor(s, off);
      float inv = __fdividef(1.f, s);
      float r = 0.f;
      for (int n = 0; n < NPG; ++n) r += att[n] * hL[n * 65 + t];
      S[t] = S[256 + t];                          // q
      S[64 + t] = r * inv;                        // readout
    }
    __syncthreads();
  }
  // predict: relu(q_star @ W_p1 + b_p1) @ W_p2 + b_p2
  if (t < 64) {
    float p = b_p1[t];
    for (int k = 0; k < 2 * D; ++k) p += S[k] * W_p1[k * D + t];
    p = fmaxf(p, 0.f);
    att[t] = p * W_p2[t];
  }
  __syncthreads();
  if (t == 0) {
    float s = 0.f;
    for (int j = 0; j < D; ++j) s += att[j];
    out[g] = s + b_p2[0];
  }
}

extern "C" void kernel_launch(void* const* d_in, const int* in_sizes, int n_in,
                              void* d_out, int out_size, void* d_ws, size_t ws_size,
                              hipStream_t stream) {
  const float* node_feats = (const float*)d_in[0];
  const float* edge_feats = (const float*)d_in[1];
  const int*   src        = (const int*)d_in[2];
  const int*   dst        = (const int*)d_in[3];
  // d_in[4] graph_ids: contiguous 100-node segments by construction
  const float* W_proj = (const float*)d_in[5];
  const float* b_proj = (const float*)d_in[6];
  const float* W_e1   = (const float*)d_in[7];
  const float* b_e1   = (const float*)d_in[8];
  const float* W_e2   = (const float*)d_in[9];
  const float* b_e2   = (const float*)d_in[10];
  const float* b_conv = (const float*)d_in[11];
  const float* W_ih   = (const float*)d_in[12];
  const float* W_hh   = (const float*)d_in[13];
  const float* b_ih   = (const float*)d_in[14];
  const float* b_hh   = (const float*)d_in[15];
  const float* Wih0 = (const float*)d_in[16]; const float* Whh0 = (const float*)d_in[17];
  const float* bih0 = (const float*)d_in[18]; const float* bhh0 = (const float*)d_in[19];
  const float* Wih1 = (const float*)d_in[20]; const float* Whh1 = (const float*)d_in[21];
  const float* bih1 = (const float*)d_in[22]; const float* bhh1 = (const float*)d_in[23];
  const float* Wih2 = (const float*)d_in[24]; const float* Whh2 = (const float*)d_in[25];
  const float* bih2 = (const float*)d_in[26]; const float* bhh2 = (const float*)d_in[27];
  const float* W_p1 = (const float*)d_in[28]; const float* b_p1 = (const float*)d_in[29];
  const float* W_p2 = (const float*)d_in[30]; const float* b_p2 = (const float*)d_in[31];

  // ---- workspace layout (base ~13.84 MB proven safe; msg path guarded) ----
  char* ws = (char*)d_ws;
  float* h      = (float*)(ws + 0);               // 1,024,000
  float* agg    = (float*)(ws + 1024000);         // 1,024,000
  u16b*  r1b    = (u16b*) (ws + 2048000);         // 10,240,000
  int*   offs   = (int*)  (ws + 12288000);        // 16,384 (4096 bins)
  int*   cursor = (int*)  (ws + 12304384);        // 16,384
  int*   order  = (int*)  (ws + 12320768);        // 160,000
  u16b*  W2s    = (u16b*) (ws + 12480768);        // 1,048,576 (fragment-permuted)
  unsigned* WP0 = (unsigned*)(ws + 13529344);     // 98,304
  unsigned* WP1 = (unsigned*)(ws + 13627648);     // 65,536
  unsigned* WP2 = (unsigned*)(ws + 13693184);     // 65,536
  float* bsum   = (float*)(ws + 13758720);        // 3,072
  u16b*  WIHf   = (u16b*) (ws + 13761792);        // 24,576
  u16b*  WHHf   = (u16b*) (ws + 13786368);        // 24,576
  u16b*  W1f    = (u16b*) (ws + 13810944);        // 32,768 -> 13,843,712
  int*   doffs   = (int*) (ws + 13843712);        // 16,384
  int*   dcursor = (int*) (ws + 13860096);        // 16,384
  int*   dorder  = (int*) (ws + 13876480);        // 160,000 -> 14,036,480
  float* msgf    = (float*)(ws + 14036480);       // 10,240,000 -> 24,276,480
  u16b*  msgb    = (u16b*) (ws + 14036480);       // 5,120,000  -> 19,156,480

  int mode = 0;                                   // constant across calls
  if (ws_size >= 24276480u) mode = 2;
  else if (ws_size >= 19156480u) mode = 1;

  k_proj<<<V_N, 64, 0, stream>>>(node_feats, W_proj, b_proj, h);
  k_prep<<<2048, 256, 0, stream>>>(W_ih, W_hh, W_e2, W_e1,
      Wih0, Whh0, bih0, bhh0, Wih1, Whh1, bih1, bhh1, Wih2, Whh2, bih2, bhh2,
      W2s, WP0, WP1, WP2, bsum, WIHf, WHHf, W1f);
  k_edge2<<<E_N / 64, 256, 0, stream>>>(edge_feats, W1f, b_e1, r1b);
  // counting sort by src
  k_zero<<<16, 256, 0, stream>>>(cursor);
  k_hist<<<(E_N + 255) / 256, 256, 0, stream>>>(src, cursor);
  k_scan<<<1, 256, 0, stream>>>(cursor, offs, cursor);
  k_scatter<<<(E_N + 255) / 256, 256, 0, stream>>>(src, cursor, order);
  if (mode > 0) {
    // counting sort by dst (for gather path)
    k_zero<<<16, 256, 0, stream>>>(dcursor);
    k_hist<<<(E_N + 255) / 256, 256, 0, stream>>>(dst, dcursor);
    k_scan<<<1, 256, 0, stream>>>(dcursor, doffs, dcursor);
    k_scatter<<<(E_N + 255) / 256, 256, 0, stream>>>(dst, dcursor, dorder);
  } else {
    k_zero_agg<<<(V_N * D) / 256, 256, 0, stream>>>(agg);
  }

  for (int s = 0; s < NSTEPS; ++s) {
    k_msg8<<<(V_N / 16) * 4, 512, 0, stream>>>(h, r1b, W2s, b_e2,
                                               offs, order, dst, agg,
                                               msgf, msgb, mode);
    k_gru4<<<V_N / 16, 256, 0, stream>>>(agg, h, msgf, msgb, mode,
                                         doffs, dorder,
                                         WIHf, WHHf, b_ih, b_hh, b_conv);
  }
  k_s2s<<<G_N, 512, 0, stream>>>(h, WP0, WP1, WP2, bsum,
      W_p1, b_p1, W_p2, b_p2, (float*)d_out);
}

// Round 13
// 504.924 us; speedup vs baseline: 1.1328x; 1.1328x over previous
//
#include <hip/hip_runtime.h>
#include <hip/hip_bf16.h>
#include <cstdint>
#include <cstddef>

#define D 64
#define V_N 4000
#define E_N 40000
#define G_N 40
#define NPG 100          // nodes per graph (contiguous)
#define NODE_IN 74
#define EDGE_IN 128
#define NSTEPS 6
#define S2S_ITERS 6

typedef unsigned short u16b;
typedef __attribute__((ext_vector_type(8))) short bf16x8;
typedef __attribute__((ext_vector_type(4))) float f32x4;

__device__ __forceinline__ float b2f(u16b u) {
  union { unsigned int i; float f; } v; v.i = ((unsigned int)u) << 16; return v.f;
}
__device__ __forceinline__ u16b f2b(float f) {
  union { unsigned int i; float f; } v; v.f = f;
  unsigned int r = (v.i + 0x7fffu + ((v.i >> 16) & 1u)) >> 16;
  return (u16b)r;
}
// fast transcendentals (v_exp + fast rcp): ~1 ulp fp32, << bf16 noise
__device__ __forceinline__ float sigf(float x) {
  return __fdividef(1.f, 1.f + __expf(-x));
}
__device__ __forceinline__ float tanhf_f(float x) {
  return 1.f - 2.f * __fdividef(1.f, __expf(2.f * x) + 1.f);
}

// ---------------- h = relu(node_feats @ W_proj + b_proj) ----------------
__global__ __launch_bounds__(256) void k_proj(
    const float* __restrict__ nf, const float* __restrict__ W,
    const float* __restrict__ b, float* __restrict__ h) {
  int t = threadIdx.x;
  int v = blockIdx.x * 4 + (t >> 6), o = t & 63;
  const float* row = nf + v * NODE_IN;
  float acc = b[o];
  for (int i = 0; i < NODE_IN; ++i)
    acc += row[i] * W[i * D + o];
  h[v * D + o] = fmaxf(acc, 0.f);
}

// ------- prep: all weight repacks (fragments + packed LSTM + bias sums) -----
__global__ void k_prep(const float* __restrict__ W_ih, const float* __restrict__ W_hh,
                       const float* __restrict__ W_e2, const float* __restrict__ W_e1,
                       const float* __restrict__ Wih0, const float* __restrict__ Whh0,
                       const float* __restrict__ bih0, const float* __restrict__ bhh0,
                       const float* __restrict__ Wih1, const float* __restrict__ Whh1,
                       const float* __restrict__ bih1, const float* __restrict__ bhh1,
                       const float* __restrict__ Wih2, const float* __restrict__ Whh2,
                       const float* __restrict__ bih2, const float* __restrict__ bhh2,
                       u16b* __restrict__ W2s,
                       unsigned* __restrict__ WP0, unsigned* __restrict__ WP1,
                       unsigned* __restrict__ WP2, float* __restrict__ bsum,
                       u16b* __restrict__ WIHf, u16b* __restrict__ WHHf,
                       u16b* __restrict__ W1f) {
  int idx = blockIdx.x * 256 + threadIdx.x;       // grid covers 524288
  if (idx < 524288) {                             // W_e2 -> Phase-A fragments
    int q = idx >> 17, rem = idx & 131071;
    int t16 = rem >> 10, rem2 = rem & 1023;
    int kbA = rem2 >> 9, rem3 = rem2 & 511;
    int lane = rem3 >> 3, jA = rem3 & 7;
    int m15 = lane & 15, quadA = lane >> 4;
    int m_idx = t16 * 16 + m15;
    int i = kbA * 32 + quadA * 8 + jA;
    int kb = m_idx >> 9, quadB = (m_idx >> 7) & 3;
    int n15B = (m_idx >> 3) & 15, j = m_idx & 7;
    int k = kb * 32 + quadB * 8 + j;
    int o = q * 16 + n15B;
    W2s[idx] = f2b(W_e2[k * 4096 + i * 64 + o]);
  }
  if (idx < 24576) {                              // WP0: layer0 packed bf16
    int kh = idx >> 8, tt = idx & 255;
    int half = kh / 48, kk = kh - half * 48;
    int k0 = half * 96 + 2 * kk;
    float v0 = (k0 < 128) ? Wih0[tt * 128 + k0] : Whh0[tt * 64 + (k0 - 128)];
    float v1 = (k0 + 1 < 128) ? Wih0[tt * 128 + k0 + 1] : Whh0[tt * 64 + (k0 - 127)];
    WP0[idx] = (unsigned)f2b(v0) | ((unsigned)f2b(v1) << 16);
  }
  if (idx < 16384) {                              // WP1/WP2: layers 1,2
    int kh = idx >> 8, tt = idx & 255;
    int half = kh >> 5, kk = kh & 31;
    int k0 = half * 64 + 2 * kk;
    float a0 = (k0 < 64) ? Wih1[tt * 64 + k0] : Whh1[tt * 64 + (k0 - 64)];
    float a1 = (k0 + 1 < 64) ? Wih1[tt * 64 + k0 + 1] : Whh1[tt * 64 + (k0 - 63)];
    WP1[idx] = (unsigned)f2b(a0) | ((unsigned)f2b(a1) << 16);
    float c0 = (k0 < 64) ? Wih2[tt * 64 + k0] : Whh2[tt * 64 + (k0 - 64)];
    float c1 = (k0 + 1 < 64) ? Wih2[tt * 64 + k0 + 1] : Whh2[tt * 64 + (k0 - 63)];
    WP2[idx] = (unsigned)f2b(c0) | ((unsigned)f2b(c1) << 16);
  }
  if (idx < 12288) {                              // GRU weights -> A-fragments
    int j = idx & 7, lane = (idx >> 3) & 63, tk = idx >> 9;
    int gt = tk >> 1, kb = tk & 1;
    int gate = gt * 16 + (lane & 15);
    int i = kb * 32 + ((lane >> 4) << 3) + j;
    WIHf[idx] = f2b(W_ih[gate * 64 + i]);
    WHHf[idx] = f2b(W_hh[gate * 64 + i]);
  }
  if (idx < 16384) {                              // W_e1 -> B-fragments
    int j = idx & 7, lane = (idx >> 3) & 63, tk = idx >> 9;
    int nt = tk >> 2, kb = tk & 3;
    int n = nt * 16 + (lane & 15);
    int i = kb * 32 + ((lane >> 4) << 3) + j;
    W1f[idx] = f2b(W_e1[i * 128 + n]);
  }
  if (idx < 256) bsum[idx] = bih0[idx] + bhh0[idx];
  else if (idx < 512) bsum[idx] = bih1[idx - 256] + bhh1[idx - 256];
  else if (idx < 768) bsum[idx] = bih2[idx - 512] + bhh2[idx - 512];
}

// -------- r1 = relu(edge_feats @ W_e1 + b_e1) -> bf16, via MFMA -------------
__global__ __launch_bounds__(256) void k_edge2(
    const float* __restrict__ ef, const u16b* __restrict__ W1f,
    const float* __restrict__ b_e1, u16b* __restrict__ r1b) {
  __shared__ __align__(16) u16b R[64 * 128];      // 16 KB
  int t = threadIdx.x, w = t >> 6, lane = t & 63;
  int n15 = lane & 15, quad = lane >> 4;
  int e0 = blockIdx.x * 64;
  int ew = e0 + w * 16;                           // wave's 16-edge m-tile
  bf16x8 aF[4];
  const float* ep = ef + (size_t)(ew + n15) * 128 + quad * 8;
#pragma unroll
  for (int kb = 0; kb < 4; ++kb) {
    union { bf16x8 v; u16b s[8]; } au;
#pragma unroll
    for (int j = 0; j < 8; ++j) au.s[j] = f2b(ep[kb * 32 + j]);
    aF[kb] = au.v;
  }
  const uint4* B4 = (const uint4*)W1f;
#pragma unroll
  for (int nt = 0; nt < 8; ++nt) {
    f32x4 acc = {0.f, 0.f, 0.f, 0.f};
#pragma unroll
    for (int kb = 0; kb < 4; ++kb) {
      union { uint4 u; bf16x8 v; } bu;
      bu.u = B4[(nt * 4 + kb) * 64 + lane];
      acc = __builtin_amdgcn_mfma_f32_16x16x32_bf16(aF[kb], bu.v, acc, 0, 0, 0);
    }
    float bb = b_e1[nt * 16 + n15];
#pragma unroll
    for (int r = 0; r < 4; ++r) {
      int eoff = w * 16 + quad * 4 + r;           // D row = edge offset
      R[eoff * 128 + nt * 16 + n15] = f2b(fmaxf(acc[r] + bb, 0.f));
    }
  }
  __syncthreads();
  const uint4* Rs = (const uint4*)R;
  uint4* out4 = (uint4*)(r1b + (size_t)e0 * 128);
  for (int i = t; i < 1024; i += 256) out4[i] = Rs[i];
}

// ---------------- counting sort of edges by src ----------------
__global__ void k_zero(int* __restrict__ cnt) {   // 4096 bins
  cnt[blockIdx.x * 256 + threadIdx.x] = 0;
}
__global__ void k_hist(const int* __restrict__ key, int* __restrict__ cnt) {
  int e = blockIdx.x * 256 + threadIdx.x;
  if (e < E_N) atomicAdd(&cnt[key[e]], 1);
}
__global__ __launch_bounds__(256) void k_scan(const int* __restrict__ cnt,
                                              int* __restrict__ offs,
                                              int* __restrict__ cursor) {
  __shared__ int part[256];
  int t = threadIdx.x;                            // single block
  int local[16], s = 0;
#pragma unroll
  for (int b = 0; b < 16; ++b) { local[b] = cnt[t * 16 + b]; s += local[b]; }
  part[t] = s;
  __syncthreads();
  for (int off = 1; off < 256; off <<= 1) {
    int v = (t >= off) ? part[t - off] : 0;
    __syncthreads();
    part[t] += v;
    __syncthreads();
  }
  int run = part[t] - s;                          // exclusive base
#pragma unroll
  for (int b = 0; b < 16; ++b) {
    offs[t * 16 + b] = run;
    cursor[t * 16 + b] = run;
    run += local[b];
  }
}
__global__ void k_scatter(const int* __restrict__ key, int* __restrict__ cursor,
                          int* __restrict__ order) {
  int e = blockIdx.x * 256 + threadIdx.x;
  if (e < E_N) {
    int pos = atomicAdd(&cursor[key[e]], 1);
    order[pos] = e;
  }
}

// ---------------- zero agg once (per-step reset happens in k_gru3) ----------
__global__ void k_zero_agg(float* __restrict__ agg) {
  agg[blockIdx.x * 256 + threadIdx.x] = 0.f;
}

// ------ block = 16 nodes x 1 o-quarter, 512 threads (8 waves).
// Phase A: T[16n][128k][16o] + ybias via MFMA. Phase B: edge-tile MFMA,
// atomic scatter to agg (proven fastest path).
__global__ __launch_bounds__(512) void k_msg7(
    const float* __restrict__ h, const u16b* __restrict__ r1b,
    const u16b* __restrict__ W2s, const float* __restrict__ b_e2,
    const int* __restrict__ offs, const int* __restrict__ order,
    const int* __restrict__ dst, float* __restrict__ agg) {
  __shared__ __align__(16) u16b TB[16 * 2048];    // 64 KB exactly
  __shared__ float ybs[16][16];
  int t = threadIdx.x;
  int g = blockIdx.x >> 2, q = blockIdx.x & 3;
  int v0 = g * 16;
  int w = t >> 6, lane = t & 63;
  int n15 = lane & 15, quad = lane >> 4;

  bf16x8 hb[2];
  {
    union { bf16x8 v; u16b s[8]; } b0, b1;
    const float* hp = h + (v0 + n15) * 64 + quad * 8;
#pragma unroll
    for (int j = 0; j < 8; ++j) { b0.s[j] = f2b(hp[j]); b1.s[j] = f2b(hp[32 + j]); }
    hb[0] = b0.v; hb[1] = b1.v;
  }
  if (w == 0) {
    union { bf16x8 v; u16b s[8]; } a0, a1;
#pragma unroll
    for (int j = 0; j < 8; ++j) {
      a0.s[j] = f2b(b_e2[(quad * 8 + j) * 64 + q * 16 + n15]);
      a1.s[j] = f2b(b_e2[(32 + quad * 8 + j) * 64 + q * 16 + n15]);
    }
    f32x4 acc = {0.f, 0.f, 0.f, 0.f};
    acc = __builtin_amdgcn_mfma_f32_16x16x32_bf16(a0.v, hb[0], acc, 0, 0, 0);
    acc = __builtin_amdgcn_mfma_f32_16x16x32_bf16(a1.v, hb[1], acc, 0, 0, 0);
#pragma unroll
    for (int r = 0; r < 4; ++r) ybs[n15][quad * 4 + r] = acc[r];
  }
  const uint4* W4 = (const uint4*)(W2s) + (size_t)q * 16384;
#pragma unroll 4
  for (int tt = 0; tt < 16; ++tt) {
    int t16 = w * 16 + tt;
    uint4 a0 = W4[t16 * 128 + lane];
    uint4 a1 = W4[t16 * 128 + 64 + lane];
    union { uint4 u; bf16x8 v; } c0, c1;
    c0.u = a0; c1.u = a1;
    f32x4 acc = {0.f, 0.f, 0.f, 0.f};
    acc = __builtin_amdgcn_mfma_f32_16x16x32_bf16(c0.v, hb[0], acc, 0, 0, 0);
    acc = __builtin_amdgcn_mfma_f32_16x16x32_bf16(c1.v, hb[1], acc, 0, 0, 0);
    int flat = (t16 * 16 + quad * 4 + n15 * 8) & 2047;
    uint2 pk;
    pk.x = (unsigned)f2b(acc[0]) | ((unsigned)f2b(acc[1]) << 16);
    pk.y = (unsigned)f2b(acc[2]) | ((unsigned)f2b(acc[3]) << 16);
    *(uint2*)&TB[n15 * 2048 + flat] = pk;
  }
  __syncthreads();

  for (int ni = 0; ni < 2; ++ni) {
    int n = w * 2 + ni;
    int v = v0 + n;
    int e0 = offs[v], e1 = offs[v + 1];
    if (e0 >= e1) continue;
    bf16x8 bfr[4];
#pragma unroll
    for (int kb = 0; kb < 4; ++kb) {
      int flat = (((kb * 64 + quad * 16 + n15) << 3) + n * 8) & 2047;
      bfr[kb] = *(const bf16x8*)&TB[n * 2048 + flat];
    }
    float yb = ybs[n][n15];
    for (int jt = e0; jt < e1; jt += 16) {
      int je = jt + n15; if (je > e1 - 1) je = e1 - 1;
      int e = order[je];
      f32x4 acc = {0.f, 0.f, 0.f, 0.f};
#pragma unroll
      for (int kb = 0; kb < 4; ++kb) {
        union { uint4 u; bf16x8 v; } af;
        af.u = *(const uint4*)(r1b + e * 128 + kb * 32 + quad * 8);
        acc = __builtin_amdgcn_mfma_f32_16x16x32_bf16(af.v, bfr[kb], acc, 0, 0, 0);
      }
#pragma unroll
      for (int r = 0; r < 4; ++r) {
        int row = quad * 4 + r;
        if (jt + row < e1) {
          int er = order[jt + row];
          atomicAdd(&agg[dst[er] * 64 + q * 16 + n15], acc[r] + yb);
        }
      }
    }
  }
}

// -------- GRU via MFMA: 4 waves/block, 1 wave = 4 nodes (1000 waves) --------
__global__ __launch_bounds__(256) void k_gru3(
    float* __restrict__ agg, float* __restrict__ h,
    const u16b* __restrict__ WIHf, const u16b* __restrict__ WHHf,
    const float* __restrict__ b_ih, const float* __restrict__ b_hh,
    const float* __restrict__ b_conv) {
  __shared__ float G[4][4][4][68];                // [wave][kind][node][dim]
  int t = threadIdx.x, w = t >> 6, lane = t & 63;
  int n15 = lane & 15, quad = lane >> 4;
  int vb = blockIdx.x * 16 + w * 4;               // wave's 4 nodes
  bf16x8 xB[2], hB[2];
  {
    union { bf16x8 v; u16b s[8]; } bx0, bx1, bh0, bh1;
#pragma unroll
    for (int j = 0; j < 8; ++j) { bx0.s[j] = 0; bx1.s[j] = 0; bh0.s[j] = 0; bh1.s[j] = 0; }
    if (n15 < 4) {
      float* ap = agg + (vb + n15) * 64 + quad * 8;
      const float* hp = h + (vb + n15) * 64 + quad * 8;
      const float* bc = b_conv + quad * 8;
#pragma unroll
      for (int j = 0; j < 8; ++j) {
        bx0.s[j] = f2b(fmaxf(ap[j] + bc[j], 0.f));
        bx1.s[j] = f2b(fmaxf(ap[32 + j] + bc[32 + j], 0.f));
        bh0.s[j] = f2b(hp[j]);
        bh1.s[j] = f2b(hp[32 + j]);
      }
      float4 z4 = make_float4(0.f, 0.f, 0.f, 0.f);
      *(float4*)ap = z4; *(float4*)(ap + 4) = z4;
      *(float4*)(ap + 32) = z4; *(float4*)(ap + 36) = z4;
    }
    xB[0] = bx0.v; xB[1] = bx1.v; hB[0] = bh0.v; hB[1] = bh1.v;
  }
  float hold[4];
#pragma unroll
  for (int n = 0; n < 4; ++n) hold[n] = h[(vb + n) * 64 + lane];
  const uint4* AIH = (const uint4*)WIHf;
  const uint4* AHH = (const uint4*)WHHf;
#pragma unroll
  for (int gt = 0; gt < 8; ++gt) {                // r (0-3) and z (4-7) blocks
    union { uint4 u; bf16x8 v; } a;
    f32x4 acc = {0.f, 0.f, 0.f, 0.f};
    a.u = AIH[(gt * 2 + 0) * 64 + lane];
    acc = __builtin_amdgcn_mfma_f32_16x16x32_bf16(a.v, xB[0], acc, 0, 0, 0);
    a.u = AIH[(gt * 2 + 1) * 64 + lane];
    acc = __builtin_amdgcn_mfma_f32_16x16x32_bf16(a.v, xB[1], acc, 0, 0, 0);
    a.u = AHH[(gt * 2 + 0) * 64 + lane];
    acc = __builtin_amdgcn_mfma_f32_16x16x32_bf16(a.v, hB[0], acc, 0, 0, 0);
    a.u = AHH[(gt * 2 + 1) * 64 + lane];
    acc = __builtin_amdgcn_mfma_f32_16x16x32_bf16(a.v, hB[1], acc, 0, 0, 0);
    int kind = (gt < 4) ? 0 : 1;
    int base = (gt & 3) * 16 + quad * 4;
    if (n15 < 4) {
#pragma unroll
      for (int r = 0; r < 4; ++r) G[w][kind][n15][base + r] = acc[r];
    }
  }
#pragma unroll
  for (int gt = 8; gt < 12; ++gt) {               // n block: keep i/h separate
    union { uint4 u; bf16x8 v; } a;
    f32x4 ai = {0.f, 0.f, 0.f, 0.f}, ah = {0.f, 0.f, 0.f, 0.f};
    a.u = AIH[(gt * 2 + 0) * 64 + lane];
    ai = __builtin_amdgcn_mfma_f32_16x16x32_bf16(a.v, xB[0], ai, 0, 0, 0);
    a.u = AIH[(gt * 2 + 1) * 64 + lane];
    ai = __builtin_amdgcn_mfma_f32_16x16x32_bf16(a.v, xB[1], ai, 0, 0, 0);
    a.u = AHH[(gt * 2 + 0) * 64 + lane];
    ah = __builtin_amdgcn_mfma_f32_16x16x32_bf16(a.v, hB[0], ah, 0, 0, 0);
    a.u = AHH[(gt * 2 + 1) * 64 + lane];
    ah = __builtin_amdgcn_mfma_f32_16x16x32_bf16(a.v, hB[1], ah, 0, 0, 0);
    int base = (gt & 3) * 16 + quad * 4;
    if (n15 < 4) {
#pragma unroll
      for (int r = 0; r < 4; ++r) { G[w][2][n15][base + r] = ai[r]; G[w][3][n15][base + r] = ah[r]; }
    }
  }
  __syncthreads();
  float bi_r = b_ih[lane] + b_hh[lane];
  float bi_z = b_ih[64 + lane] + b_hh[64 + lane];
  float bi_n1 = b_ih[128 + lane], bi_n2 = b_hh[128 + lane];
#pragma unroll
  for (int n = 0; n < 4; ++n) {
    float r = sigf(G[w][0][n][lane] + bi_r);
    float z = sigf(G[w][1][n][lane] + bi_z);
    float nn = tanhf_f(G[w][2][n][lane] + bi_n1 + r * (G[w][3][n][lane] + bi_n2));
    h[(vb + n) * 64 + lane] = (1.f - z) * nn + z * hold[n];
  }
}

// ------- Set2Set: round-12 proven body (48.5 us, no spills) -----------------
__global__ __launch_bounds__(512) void k_s2s(
    const float* __restrict__ h,
    const unsigned* __restrict__ WP0, const unsigned* __restrict__ WP1,
    const unsigned* __restrict__ WP2, const float* __restrict__ bsum,
    const float* __restrict__ W_p1, const float* __restrict__ b_p1,
    const float* __restrict__ W_p2, const float* __restrict__ b_p2,
    float* __restrict__ out) {
  int g = blockIdx.x, t = threadIdx.x;            // 512 threads
  int tt = t & 255, half = t >> 8;
  __shared__ float hL[NPG * 65];
  __shared__ float S[320];                        // [q_star(128)|hs0|hs1|hs2]
  __shared__ float csL[3][64];
  __shared__ float gpart[512], att[NPG];
  unsigned w0[48], w1[32], w2[32];
#pragma unroll
  for (int kk = 0; kk < 48; ++kk) w0[kk] = WP0[(half * 48 + kk) * 256 + tt];
#pragma unroll
  for (int kk = 0; kk < 32; ++kk) w1[kk] = WP1[(half * 32 + kk) * 256 + tt];
#pragma unroll
  for (int kk = 0; kk < 32; ++kk) w2[kk] = WP2[(half * 32 + kk) * 256 + tt];
  for (int idx = t; idx < NPG * 64; idx += 512)
    hL[(idx >> 6) * 65 + (idx & 63)] = h[(size_t)g * NPG * 64 + idx];
  if (t < 320) S[t] = 0.f;
  if (t < 192) ((float*)csL)[t] = 0.f;
  __syncthreads();
  for (int it = 0; it < S2S_ITERS; ++it) {
    // ---- layer 0: window S+0 (len 192) ----
    {
      const float* win = S + half * 96;
      float p = 0.f;
#pragma unroll
      for (int kk = 0; kk < 48; ++kk) {
        unsigned wv = w0[kk];
        p += b2f((u16b)(wv & 0xffffu)) * win[2 * kk]
           + b2f((u16b)(wv >> 16)) * win[2 * kk + 1];
      }
      gpart[t] = p;
    }
    __syncthreads();
    if (t < 64) {
      float gi = bsum[t]       + gpart[t]       + gpart[t + 256];
      float gf = bsum[64 + t]  + gpart[64 + t]  + gpart[64 + t + 256];
      float gg = bsum[128 + t] + gpart[128 + t] + gpart[128 + t + 256];
      float go = bsum[192 + t] + gpart[192 + t] + gpart[192 + t + 256];
      float c = sigf(gf) * csL[0][t] + sigf(gi) * tanhf_f(gg);
      csL[0][t] = c;
      S[128 + t] = sigf(go) * tanhf_f(c);
    }
    __syncthreads();
    // ---- layer 1: window S+128 (len 128) ----
    {
      const float* win = S + 128 + half * 64;
      float p = 0.f;
#pragma unroll
      for (int kk = 0; kk < 32; ++kk) {
        unsigned wv = w1[kk];
        p += b2f((u16b)(wv & 0xffffu)) * win[2 * kk]
           + b2f((u16b)(wv >> 16)) * win[2 * kk + 1];
      }
      gpart[t] = p;
    }
    __syncthreads();
    if (t < 64) {
      float gi = bsum[256 + t]       + gpart[t]       + gpart[t + 256];
      float gf = bsum[256 + 64 + t]  + gpart[64 + t]  + gpart[64 + t + 256];
      float gg = bsum[256 + 128 + t] + gpart[128 + t] + gpart[128 + t + 256];
      float go = bsum[256 + 192 + t] + gpart[192 + t] + gpart[192 + t + 256];
      float c = sigf(gf) * csL[1][t] + sigf(gi) * tanhf_f(gg);
      csL[1][t] = c;
      S[192 + t] = sigf(go) * tanhf_f(c);
    }
    __syncthreads();
    // ---- layer 2: window S+192 (len 128) ----
    {
      const float* win = S + 192 + half * 64;
      float p = 0.f;
#pragma unroll
      for (int kk = 0; kk < 32; ++kk) {
        unsigned wv = w2[kk];
        p += b2f((u16b)(wv & 0xffffu)) * win[2 * kk]
           + b2f((u16b)(wv >> 16)) * win[2 * kk + 1];
      }
      gpart[t] = p;
    }
    __syncthreads();
    if (t < 64) {
      float gi = bsum[512 + t]       + gpart[t]       + gpart[t + 256];
      float gf = bsum[512 + 64 + t]  + gpart[64 + t]  + gpart[64 + t + 256];
      float gg = bsum[512 + 128 + t] + gpart[128 + t] + gpart[128 + t + 256];
      float go = bsum[512 + 192 + t] + gpart[192 + t] + gpart[192 + t + 256];
      float c = sigf(gf) * csL[2][t] + sigf(gi) * tanhf_f(gg);
      csL[2][t] = c;
      S[256 + t] = sigf(go) * tanhf_f(c);
    }
    __syncthreads();
    // ---- attention scores (threads 0..99) ----
    if (t < NPG) {
      float e = 0.f;
#pragma unroll 8
      for (int dd = 0; dd < D; ++dd) e += hL[t * 65 + dd] * S[256 + dd];
      att[t] = e;
    }
    __syncthreads();
    // ---- wave 0: softmax + readout + q_star update (wave-synchronous) ----
    if (t < 64) {
      float m = att[t];
      if (t < NPG - 64) m = fmaxf(m, att[t + 64]);
#pragma unroll
      for (int off = 32; off >= 1; off >>= 1) m = fmaxf(m, __shfl_xor(m, off));
      float e1 = __expf(att[t] - m);
      float e2 = (t < NPG - 64) ? __expf(att[t + 64] - m) : 0.f;
      att[t] = e1;
      if (t < NPG - 64) att[t + 64] = e2;
      float s = e1 + e2;
#pragma unroll
      for (int off = 32; off >= 1; off >>= 1) s += __shfl_xor(s, off);
      float inv = __fdividef(1.f, s);
      float r = 0.f;
      for (int n = 0; n < NPG; ++n) r += att[n] * hL[n * 65 + t];
      S[t] = S[256 + t];                          // q
      S[64 + t] = r * inv;                        // readout
    }
    __syncthreads();
  }
  // predict: relu(q_star @ W_p1 + b_p1) @ W_p2 + b_p2
  if (t < 64) {
    float p = b_p1[t];
    for (int k = 0; k < 2 * D; ++k) p += S[k] * W_p1[k * D + t];
    p = fmaxf(p, 0.f);
    att[t] = p * W_p2[t];
  }
  __syncthreads();
  if (t == 0) {
    float s = 0.f;
    for (int j = 0; j < D; ++j) s += att[j];
    out[g] = s + b_p2[0];
  }
}

extern "C" void kernel_launch(void* const* d_in, const int* in_sizes, int n_in,
                              void* d_out, int out_size, void* d_ws, size_t ws_size,
                              hipStream_t stream) {
  const float* node_feats = (const float*)d_in[0];
  const float* edge_feats = (const float*)d_in[1];
  const int*   src        = (const int*)d_in[2];
  const int*   dst        = (const int*)d_in[3];
  // d_in[4] graph_ids: contiguous 100-node segments by construction
  const float* W_proj = (const float*)d_in[5];
  const float* b_proj = (const float*)d_in[6];
  const float* W_e1   = (const float*)d_in[7];
  const float* b_e1   = (const float*)d_in[8];
  const float* W_e2   = (const float*)d_in[9];
  const float* b_e2   = (const float*)d_in[10];
  const float* b_conv = (const float*)d_in[11];
  const float* W_ih   = (const float*)d_in[12];
  const float* W_hh   = (const float*)d_in[13];
  const float* b_ih   = (const float*)d_in[14];
  const float* b_hh   = (const float*)d_in[15];
  const float* Wih0 = (const float*)d_in[16]; const float* Whh0 = (const float*)d_in[17];
  const float* bih0 = (const float*)d_in[18]; const float* bhh0 = (const float*)d_in[19];
  const float* Wih1 = (const float*)d_in[20]; const float* Whh1 = (const float*)d_in[21];
  const float* bih1 = (const float*)d_in[22]; const float* bhh1 = (const float*)d_in[23];
  const float* Wih2 = (const float*)d_in[24]; const float* Whh2 = (const float*)d_in[25];
  const float* bih2 = (const float*)d_in[26]; const float* bhh2 = (const float*)d_in[27];
  const float* W_p1 = (const float*)d_in[28]; const float* b_p1 = (const float*)d_in[29];
  const float* W_p2 = (const float*)d_in[30]; const float* b_p2 = (const float*)d_in[31];

  // ---- workspace layout (total ~13.84 MB; <= proven-safe 14.65 MB) ----
  char* ws = (char*)d_ws;
  float* h      = (float*)(ws + 0);               // 1,024,000
  float* agg    = (float*)(ws + 1024000);         // 1,024,000
  u16b*  r1b    = (u16b*) (ws + 2048000);         // 10,240,000
  int*   offs   = (int*)  (ws + 12288000);        // 16,384 (4096 bins)
  int*   cursor = (int*)  (ws + 12304384);        // 16,384
  int*   order  = (int*)  (ws + 12320768);        // 160,000
  u16b*  W2s    = (u16b*) (ws + 12480768);        // 1,048,576 (fragment-permuted)
  unsigned* WP0 = (unsigned*)(ws + 13529344);     // 98,304
  unsigned* WP1 = (unsigned*)(ws + 13627648);     // 65,536
  unsigned* WP2 = (unsigned*)(ws + 13693184);     // 65,536
  float* bsum   = (float*)(ws + 13758720);        // 3,072
  u16b*  WIHf   = (u16b*) (ws + 13761792);        // 24,576
  u16b*  WHHf   = (u16b*) (ws + 13786368);        // 24,576
  u16b*  W1f    = (u16b*) (ws + 13810944);        // 32,768 -> end 13,843,712

  k_proj<<<V_N / 4, 256, 0, stream>>>(node_feats, W_proj, b_proj, h);
  k_prep<<<2048, 256, 0, stream>>>(W_ih, W_hh, W_e2, W_e1,
      Wih0, Whh0, bih0, bhh0, Wih1, Whh1, bih1, bhh1, Wih2, Whh2, bih2, bhh2,
      W2s, WP0, WP1, WP2, bsum, WIHf, WHHf, W1f);
  k_edge2<<<E_N / 64, 256, 0, stream>>>(edge_feats, W1f, b_e1, r1b);
  // counting sort by src
  k_zero<<<16, 256, 0, stream>>>(cursor);
  k_hist<<<(E_N + 255) / 256, 256, 0, stream>>>(src, cursor);
  k_scan<<<1, 256, 0, stream>>>(cursor, offs, cursor);
  k_scatter<<<(E_N + 255) / 256, 256, 0, stream>>>(src, cursor, order);
  k_zero_agg<<<(V_N * D) / 256, 256, 0, stream>>>(agg);

  for (int s = 0; s < NSTEPS; ++s) {
    k_msg7<<<(V_N / 16) * 4, 512, 0, stream>>>(h, r1b, W2s, b_e2,
                                               offs, order, dst, agg);
    k_gru3<<<V_N / 16, 256, 0, stream>>>(agg, h, WIHf, WHHf, b_ih, b_hh, b_conv);
  }
  k_s2s<<<G_N, 512, 0, stream>>>(h, WP0, WP1, WP2, bsum,
      W_p1, b_p1, W_p2, b_p2, (float*)d_out);
}